// Round 1
// baseline (179.686 us; speedup 1.0000x reference)
//
#include <hip/hip_runtime.h>
#include <hip/hip_bf16.h>

// Problem: MultiViewDGT_51745765982512
// Per-sample portfolio vector with leave-one-out correction.
//   Inputs (fp32/int32):
//     d_in[0] H                  [N, 128] fp32
//     d_in[1] port_w_signed_flat [L] fp32
//     d_in[2] anchor_idx         [B] int32
//     d_in[3] pf_gid             [B] int32
//     d_in[4] port_nodes_flat    [L] int32
//     d_in[5] port_len           [G] int32
//   Output: concat(V_abs [B,128], V_sgn [B,128]) fp32
//
// Strategy: one wave (64 lanes) per sample. Each lane owns 2 dims (float2).
// Group aggregation (segment sum over that sample's group) is fused into the
// per-sample kernel: B == G and pf_gid is ~uniform, so total gather traffic is
// identical to a separate segment-sum pass, and we skip an 8 MB S_abs
// round-trip through workspace. H (32 MB) lives in L2/L3, so the 64
// row-gathers per wave (512 B each, one coalesced transaction) are cache BW.

#define WAVE 64

__global__ void scan_offsets_kernel(const int* __restrict__ len,
                                    int* __restrict__ offs, int G) {
    // Exclusive prefix sum of port_len -> group start offsets. G ~ 16384.
    __shared__ int sums[256];
    const int t = threadIdx.x;
    const int chunk = (G + 255) / 256;
    const int lo = t * chunk;
    const int hi = min(lo + chunk, G);
    int s = 0;
    for (int i = lo; i < hi; ++i) s += len[i];
    sums[t] = s;
    __syncthreads();
    if (t == 0) {
        int run = 0;
        for (int i = 0; i < 256; ++i) { int v = sums[i]; sums[i] = run; run += v; }
    }
    __syncthreads();
    int run = sums[t];
    for (int i = lo; i < hi; ++i) { offs[i] = run; run += len[i]; }
}

__global__ __launch_bounds__(256) void pf_loo_kernel(
    const float* __restrict__ H,
    const float* __restrict__ pw,
    const int* __restrict__ anchor_idx,
    const int* __restrict__ pf_gid,
    const int* __restrict__ pn,
    const int* __restrict__ plen,
    const int* __restrict__ offs,
    float* __restrict__ out,   // [2*B*128]: V_abs then V_sgn
    int B, int G) {
    const int wavesPerBlock = blockDim.x >> 6;
    const int b = blockIdx.x * wavesPerBlock + (threadIdx.x >> 6);
    const int lane = threadIdx.x & 63;
    if (b >= B) return;

    float2* outA = (float2*)(out + (size_t)b * 128);
    float2* outS = (float2*)(out + ((size_t)B + b) * 128);

    const int gid = pf_gid[b];
    const bool valid = (gid >= 0) && (gid < G);
    if (!valid) {
        outA[lane] = make_float2(0.f, 0.f);
        outS[lane] = make_float2(0.f, 0.f);
        return;
    }

    const int anchor = anchor_idx[b];
    const int off = offs[gid];
    const int len = plen[gid];

    float2 acc = make_float2(0.f, 0.f);
    float Wa = 0.f, Ws = 0.f, selfa = 0.f, selfs = 0.f;

    for (int base = 0; base < len; base += WAVE) {
        const int jmax = min(WAVE, len - base);
        // per-lane pass: W sums + LOO self-weight
        if (lane < jmax) {
            const float w = pw[off + base + lane];
            const int n = pn[off + base + lane];
            const float wa = fabsf(w);
            Wa += wa;
            Ws += w;
            if (n == anchor) { selfa += wa; selfs += w; }
        }
        // vector accumulation: lane owns dims {2*lane, 2*lane+1}
        #pragma unroll 4
        for (int j = 0; j < jmax; ++j) {
            const float w = pw[off + base + j];   // wave-uniform -> scalar load
            const int n = pn[off + base + j];     // wave-uniform -> scalar load
            const float wa = fabsf(w);
            const float2 h = ((const float2*)(H + (size_t)n * 128))[lane];
            acc.x = fmaf(wa, h.x, acc.x);
            acc.y = fmaf(wa, h.y, acc.y);
        }
    }

    // wave butterfly reductions (all lanes end with identical totals)
    #pragma unroll
    for (int m = 32; m; m >>= 1) {
        Wa += __shfl_xor(Wa, m);
        Ws += __shfl_xor(Ws, m);
        selfa += __shfl_xor(selfa, m);
        selfs += __shfl_xor(selfs, m);
    }

    const float denom = fmaxf(Wa - selfa, 1e-12f);
    const float2 hv = ((const float2*)(H + (size_t)anchor * 128))[lane];

    float2 v;
    v.x = (acc.x - selfa * hv.x) / denom;
    v.y = (acc.y - selfa * hv.y) / denom;
    const float scale = (Ws - selfs) / denom;

    float n2 = v.x * v.x + v.y * v.y;
    #pragma unroll
    for (int m = 32; m; m >>= 1) n2 += __shfl_xor(n2, m);
    const float na = sqrtf(n2);

    const float invA = 1.0f / fmaxf(na, 1e-6f);
    const float ns = fabsf(scale) * na;                 // ||scale * v||
    const float sgnscale = (ns > 0.f) ? (scale / fmaxf(ns, 1e-6f)) : scale;

    outA[lane] = make_float2(v.x * invA, v.y * invA);
    outS[lane] = make_float2(v.x * sgnscale, v.y * sgnscale);
}

extern "C" void kernel_launch(void* const* d_in, const int* in_sizes, int n_in,
                              void* d_out, int out_size, void* d_ws, size_t ws_size,
                              hipStream_t stream) {
    const float* H      = (const float*)d_in[0];
    const float* pw     = (const float*)d_in[1];
    const int* anchor   = (const int*)d_in[2];
    const int* gid      = (const int*)d_in[3];
    const int* pn       = (const int*)d_in[4];
    const int* plen     = (const int*)d_in[5];
    float* out          = (float*)d_out;

    const int B = in_sizes[2];
    const int G = in_sizes[5];

    int* offs = (int*)d_ws;   // G ints

    scan_offsets_kernel<<<1, 256, 0, stream>>>(plen, offs, G);

    const int wavesPerBlock = 4;  // 256 threads
    const int blocks = (B + wavesPerBlock - 1) / wavesPerBlock;
    pf_loo_kernel<<<blocks, 256, 0, stream>>>(H, pw, anchor, gid, pn, plen,
                                              offs, out, B, G);
}

// Round 2
// 172.375 us; speedup vs baseline: 1.0424x; 1.0424x over previous
//
#include <hip/hip_runtime.h>
#include <hip/hip_bf16.h>

// Problem: MultiViewDGT_51745765982512
//   d_in[0] H [N,128] f32, d_in[1] port_w [L] f32, d_in[2] anchor [B] i32,
//   d_in[3] pf_gid [B] i32, d_in[4] port_nodes [L] i32, d_in[5] port_len [G] i32
//   out = concat(V_abs [B,128], V_sgn [B,128]) f32
//
// R2: (a) parallel scan (1024 thr + LDS Hillis-Steele) — R1's serial scan was
//     ~100us of the 180us total. (b) gather restructured: wave split into two
//     32-lane halves, each half loads float4 (16B/lane) from its own row ->
//     2 rows per global_load_dwordx4 (1 KiB/instr, coalescing sweet spot),
//     32 loads/sample instead of 64. (w,node) broadcast via __shfl from
//     preloaded registers; stats per-lane + one butterfly at the end.

__global__ __launch_bounds__(1024) void scan_offsets_kernel(
    const int* __restrict__ len, int* __restrict__ offs, int G) {
    __shared__ int part[1024];
    const int t = threadIdx.x;
    const int chunk = (G + 1023) >> 10;
    const int lo = min(t * chunk, G);
    const int hi = min(lo + chunk, G);
    int s = 0;
    for (int i = lo; i < hi; ++i) s += len[i];
    part[t] = s;
    __syncthreads();
    // Hillis-Steele inclusive scan over 1024 partials
    #pragma unroll
    for (int ofs = 1; ofs < 1024; ofs <<= 1) {
        int v = (t >= ofs) ? part[t - ofs] : 0;
        __syncthreads();
        part[t] += v;
        __syncthreads();
    }
    int run = part[t] - s;  // exclusive
    for (int i = lo; i < hi; ++i) { offs[i] = run; run += len[i]; }
}

__global__ __launch_bounds__(256) void pf_loo_kernel(
    const float* __restrict__ H,
    const float* __restrict__ pw,
    const int* __restrict__ anchor_idx,
    const int* __restrict__ pf_gid,
    const int* __restrict__ pn,
    const int* __restrict__ plen,
    const int* __restrict__ offs,
    float* __restrict__ out,   // [2*B*128]: V_abs then V_sgn
    int B, int G) {
    const int b = blockIdx.x * (blockDim.x >> 6) + (threadIdx.x >> 6);
    const int lane = threadIdx.x & 63;
    const int half = lane >> 5;     // 0: even rows, 1: odd rows
    const int qlane = lane & 31;    // owns dims [4*qlane, 4*qlane+4)
    if (b >= B) return;

    float4* outA = (float4*)(out + (size_t)b * 128);
    float4* outS = (float4*)(out + ((size_t)B + b) * 128);

    const int gid = pf_gid[b];
    if (!(gid >= 0 && gid < G)) {
        float4 z = make_float4(0.f, 0.f, 0.f, 0.f);
        if (half == 0) { outA[qlane] = z; outS[qlane] = z; }
        return;
    }

    const int anchor = anchor_idx[b];
    const int off = offs[gid];
    const int len = plen[gid];

    float4 acc = make_float4(0.f, 0.f, 0.f, 0.f);
    float laWa = 0.f, laWs = 0.f, laSa = 0.f, laSs = 0.f;

    for (int base = 0; base < len; base += 64) {
        const int jmax = min(64, len - base);
        // preload this chunk's (w, node) into per-lane registers
        float wl = 0.f;
        int nl = 0;   // w=0 => contributes nothing; H[0] load harmless
        if (lane < jmax) {
            wl = pw[off + base + lane];
            nl = pn[off + base + lane];
        }
        const float wla = fabsf(wl);
        laWa += wla;
        laWs += wl;
        if (nl == anchor && lane < jmax) { laSa += wla; laSs += wl; }

        // 2 rows per iteration: half 0 -> row jj, half 1 -> row jj+1
        #pragma unroll 8
        for (int jj = 0; jj < 64; jj += 2) {
            const float w0 = __shfl(wl, jj);
            const float w1 = __shfl(wl, jj + 1);
            const int n0 = __shfl(nl, jj);
            const int n1 = __shfl(nl, jj + 1);
            const int row = half ? n1 : n0;
            const float ww = fabsf(half ? w1 : w0);
            const float4 h = ((const float4*)(H + (size_t)row * 128))[qlane];
            acc.x = fmaf(ww, h.x, acc.x);
            acc.y = fmaf(ww, h.y, acc.y);
            acc.z = fmaf(ww, h.z, acc.z);
            acc.w = fmaf(ww, h.w, acc.w);
        }
    }

    // stats butterfly (all 64 lanes -> uniform totals)
    #pragma unroll
    for (int m = 32; m; m >>= 1) {
        laWa += __shfl_xor(laWa, m);
        laWs += __shfl_xor(laWs, m);
        laSa += __shfl_xor(laSa, m);
        laSs += __shfl_xor(laSs, m);
    }
    // combine even/odd halves: every lane ends with full sum for its 4 dims
    acc.x += __shfl_xor(acc.x, 32);
    acc.y += __shfl_xor(acc.y, 32);
    acc.z += __shfl_xor(acc.z, 32);
    acc.w += __shfl_xor(acc.w, 32);

    const float denom = fmaxf(laWa - laSa, 1e-12f);
    const float4 hv = ((const float4*)(H + (size_t)anchor * 128))[qlane];

    float4 v;
    v.x = (acc.x - laSa * hv.x) / denom;
    v.y = (acc.y - laSa * hv.y) / denom;
    v.z = (acc.z - laSa * hv.z) / denom;
    v.w = (acc.w - laSa * hv.w) / denom;
    const float scale = (laWs - laSs) / denom;

    float n2 = v.x * v.x + v.y * v.y + v.z * v.z + v.w * v.w;
    #pragma unroll
    for (int m = 32; m; m >>= 1) n2 += __shfl_xor(n2, m);
    n2 *= 0.5f;   // halves hold duplicated v -> butterfly double-counts
    const float na = sqrtf(n2);

    const float invA = 1.0f / fmaxf(na, 1e-6f);
    const float ns = fabsf(scale) * na;                 // ||scale * v||
    const float sgnscale = (ns > 0.f) ? (scale / fmaxf(ns, 1e-6f)) : scale;

    // half 0 stores V_abs, half 1 stores V_sgn — one dwordx4 store, no divergence
    const float s = half ? sgnscale : invA;
    float4 res;
    res.x = v.x * s; res.y = v.y * s; res.z = v.z * s; res.w = v.w * s;
    float4* dst = half ? outS : outA;
    dst[qlane] = res;
}

extern "C" void kernel_launch(void* const* d_in, const int* in_sizes, int n_in,
                              void* d_out, int out_size, void* d_ws, size_t ws_size,
                              hipStream_t stream) {
    const float* H      = (const float*)d_in[0];
    const float* pw     = (const float*)d_in[1];
    const int* anchor   = (const int*)d_in[2];
    const int* gid      = (const int*)d_in[3];
    const int* pn       = (const int*)d_in[4];
    const int* plen     = (const int*)d_in[5];
    float* out          = (float*)d_out;

    const int B = in_sizes[2];
    const int G = in_sizes[5];

    int* offs = (int*)d_ws;   // G ints

    scan_offsets_kernel<<<1, 1024, 0, stream>>>(plen, offs, G);

    const int wavesPerBlock = 4;  // 256 threads
    const int blocks = (B + wavesPerBlock - 1) / wavesPerBlock;
    pf_loo_kernel<<<blocks, 256, 0, stream>>>(H, pw, anchor, gid, pn, plen,
                                              offs, out, B, G);
}

// Round 3
// 147.275 us; speedup vs baseline: 1.2201x; 1.1704x over previous
//
#include <hip/hip_runtime.h>
#include <hip/hip_bf16.h>

// Problem: MultiViewDGT_51745765982512
//   d_in[0] H [N,128] f32, d_in[1] port_w [L] f32, d_in[2] anchor [B] i32,
//   d_in[3] pf_gid [B] i32, d_in[4] port_nodes [L] i32, d_in[5] port_len [G] i32
//   out = concat(V_abs [B,128], V_sgn [B,128]) f32
//
// R3: pf_loo is bound by the L2-miss path: FETCH 240 MB = 8 XCDs x 30 MB
// (each XCD's 4 MiB L2 re-fetches the whole 32 MB H from L3 at ~3.15 TB/s).
// Fix: convert H to bf16 in workspace (16 MB -> per-XCD fill halves), gather
// 4 rows per dwordx4 (64 lanes x 16B = 4 x 256B rows; quarter-wave per row,
// lane owns 8 dims). Scan and harness overhead (~95us, fixed) unchanged.

__global__ __launch_bounds__(1024) void scan_offsets_kernel(
    const int* __restrict__ len, int* __restrict__ offs, int G) {
    __shared__ int part[1024];
    const int t = threadIdx.x;
    const int chunk = (G + 1023) >> 10;
    const int lo = min(t * chunk, G);
    const int hi = min(lo + chunk, G);
    int s = 0;
    for (int i = lo; i < hi; ++i) s += len[i];
    part[t] = s;
    __syncthreads();
    #pragma unroll
    for (int ofs = 1; ofs < 1024; ofs <<= 1) {
        int v = (t >= ofs) ? part[t - ofs] : 0;
        __syncthreads();
        part[t] += v;
        __syncthreads();
    }
    int run = part[t] - s;  // exclusive
    for (int i = lo; i < hi; ++i) { offs[i] = run; run += len[i]; }
}

__device__ inline unsigned bf_rne(float x) {
    unsigned u = __float_as_uint(x);
    return (u + 0x7FFFu + ((u >> 16) & 1u)) >> 16;
}

__global__ __launch_bounds__(256) void convert_h_kernel(
    const float4* __restrict__ H4, uint2* __restrict__ Hb, int n4) {
    const int i = blockIdx.x * blockDim.x + threadIdx.x;
    if (i >= n4) return;
    const float4 v = H4[i];
    uint2 o;
    o.x = bf_rne(v.x) | (bf_rne(v.y) << 16);
    o.y = bf_rne(v.z) | (bf_rne(v.w) << 16);
    Hb[i] = o;
}

__device__ inline void unpack2(unsigned d, float& lo, float& hi) {
    lo = __uint_as_float(d << 16);
    hi = __uint_as_float(d & 0xFFFF0000u);
}

// bf16-H gather: 4 rows per dwordx4. quarter q = lane>>4 handles row slot
// jj+q; s = lane&15 owns dims [8s, 8s+8).
__global__ __launch_bounds__(256) void pf_loo_bf16(
    const unsigned short* __restrict__ Hb,   // [N,128] bf16
    const float* __restrict__ pw,
    const int* __restrict__ anchor_idx,
    const int* __restrict__ pf_gid,
    const int* __restrict__ pn,
    const int* __restrict__ plen,
    const int* __restrict__ offs,
    float* __restrict__ out, int B, int G) {
    const int b = blockIdx.x * (blockDim.x >> 6) + (threadIdx.x >> 6);
    const int lane = threadIdx.x & 63;
    const int q = lane >> 4;
    const int s = lane & 15;
    if (b >= B) return;

    float4* outA = (float4*)(out + (size_t)b * 128);
    float4* outS = (float4*)(out + ((size_t)B + b) * 128);

    const int gid = pf_gid[b];
    if (!(gid >= 0 && gid < G)) {
        const float4 z = make_float4(0.f, 0.f, 0.f, 0.f);
        if (q == 0) { outA[2 * s] = z; outA[2 * s + 1] = z; }
        if (q == 1) { outS[2 * s] = z; outS[2 * s + 1] = z; }
        return;
    }

    const int anchor = anchor_idx[b];
    const int off = offs[gid];
    const int len = plen[gid];

    float acc[8] = {0.f, 0.f, 0.f, 0.f, 0.f, 0.f, 0.f, 0.f};
    float laWa = 0.f, laWs = 0.f, laSa = 0.f, laSs = 0.f;

    for (int base = 0; base < len; base += 64) {
        const int jmax = min(64, len - base);
        float wl = 0.f;
        int nl = 0;  // padding: w=0 contributes nothing; row-0 load harmless
        if (lane < jmax) {
            wl = pw[off + base + lane];
            nl = pn[off + base + lane];
        }
        const float wla = fabsf(wl);
        laWa += wla;
        laWs += wl;
        if (nl == anchor) { laSa += wla; laSs += wl; }  // wla==0 for pads

        #pragma unroll 8
        for (int jj = 0; jj < 64; jj += 4) {
            const float ww = fabsf(__shfl(wl, jj + q));
            const int row = __shfl(nl, jj + q);
            const uint4 h = *((const uint4*)(Hb + (size_t)row * 128) + s);
            float f0, f1, f2, f3, f4, f5, f6, f7;
            unpack2(h.x, f0, f1);
            unpack2(h.y, f2, f3);
            unpack2(h.z, f4, f5);
            unpack2(h.w, f6, f7);
            acc[0] = fmaf(ww, f0, acc[0]);
            acc[1] = fmaf(ww, f1, acc[1]);
            acc[2] = fmaf(ww, f2, acc[2]);
            acc[3] = fmaf(ww, f3, acc[3]);
            acc[4] = fmaf(ww, f4, acc[4]);
            acc[5] = fmaf(ww, f5, acc[5]);
            acc[6] = fmaf(ww, f6, acc[6]);
            acc[7] = fmaf(ww, f7, acc[7]);
        }
    }

    // stats butterfly -> uniform totals on all lanes
    #pragma unroll
    for (int m = 32; m; m >>= 1) {
        laWa += __shfl_xor(laWa, m);
        laWs += __shfl_xor(laWs, m);
        laSa += __shfl_xor(laSa, m);
        laSs += __shfl_xor(laSs, m);
    }
    // combine quarters: every lane ends with full sums for its 8-dim slice
    #pragma unroll
    for (int k = 0; k < 8; ++k) {
        acc[k] += __shfl_xor(acc[k], 16);
        acc[k] += __shfl_xor(acc[k], 32);
    }

    const float denom = fmaxf(laWa - laSa, 1e-12f);
    // anchor row in bf16 for exact cancellation with the accumulated sum
    const uint4 ha = *((const uint4*)(Hb + (size_t)anchor * 128) + s);
    float h0, h1, h2, h3, h4, h5, h6, h7;
    unpack2(ha.x, h0, h1);
    unpack2(ha.y, h2, h3);
    unpack2(ha.z, h4, h5);
    unpack2(ha.w, h6, h7);
    const float hv[8] = {h0, h1, h2, h3, h4, h5, h6, h7};

    float v[8];
    float n2 = 0.f;
    #pragma unroll
    for (int k = 0; k < 8; ++k) {
        v[k] = (acc[k] - laSa * hv[k]) / denom;
        n2 = fmaf(v[k], v[k], n2);
    }
    const float scale = (laWs - laSs) / denom;

    #pragma unroll
    for (int m = 32; m; m >>= 1) n2 += __shfl_xor(n2, m);
    n2 *= 0.25f;  // 4 duplicated quarters
    const float na = sqrtf(n2);

    const float invA = 1.0f / fmaxf(na, 1e-6f);
    const float ns = fabsf(scale) * na;
    const float sgnscale = (ns > 0.f) ? (scale / fmaxf(ns, 1e-6f)) : scale;

    if (q == 0) {
        outA[2 * s] = make_float4(v[0] * invA, v[1] * invA, v[2] * invA, v[3] * invA);
        outA[2 * s + 1] = make_float4(v[4] * invA, v[5] * invA, v[6] * invA, v[7] * invA);
    } else if (q == 1) {
        outS[2 * s] = make_float4(v[0] * sgnscale, v[1] * sgnscale, v[2] * sgnscale, v[3] * sgnscale);
        outS[2 * s + 1] = make_float4(v[4] * sgnscale, v[5] * sgnscale, v[6] * sgnscale, v[7] * sgnscale);
    }
}

// fp32 fallback (R2 structure) if ws can't hold bf16 H
__global__ __launch_bounds__(256) void pf_loo_f32(
    const float* __restrict__ H, const float* __restrict__ pw,
    const int* __restrict__ anchor_idx, const int* __restrict__ pf_gid,
    const int* __restrict__ pn, const int* __restrict__ plen,
    const int* __restrict__ offs, float* __restrict__ out, int B, int G) {
    const int b = blockIdx.x * (blockDim.x >> 6) + (threadIdx.x >> 6);
    const int lane = threadIdx.x & 63;
    const int half = lane >> 5;
    const int qlane = lane & 31;
    if (b >= B) return;
    float4* outA = (float4*)(out + (size_t)b * 128);
    float4* outS = (float4*)(out + ((size_t)B + b) * 128);
    const int gid = pf_gid[b];
    if (!(gid >= 0 && gid < G)) {
        float4 z = make_float4(0.f, 0.f, 0.f, 0.f);
        if (half == 0) { outA[qlane] = z; outS[qlane] = z; }
        return;
    }
    const int anchor = anchor_idx[b];
    const int off = offs[gid];
    const int len = plen[gid];
    float4 acc = make_float4(0.f, 0.f, 0.f, 0.f);
    float laWa = 0.f, laWs = 0.f, laSa = 0.f, laSs = 0.f;
    for (int base = 0; base < len; base += 64) {
        const int jmax = min(64, len - base);
        float wl = 0.f;
        int nl = 0;
        if (lane < jmax) { wl = pw[off + base + lane]; nl = pn[off + base + lane]; }
        const float wla = fabsf(wl);
        laWa += wla; laWs += wl;
        if (nl == anchor) { laSa += wla; laSs += wl; }
        #pragma unroll 8
        for (int jj = 0; jj < 64; jj += 2) {
            const float ww = fabsf(__shfl(wl, jj + half));
            const int row = __shfl(nl, jj + half);
            const float4 h = ((const float4*)(H + (size_t)row * 128))[qlane];
            acc.x = fmaf(ww, h.x, acc.x);
            acc.y = fmaf(ww, h.y, acc.y);
            acc.z = fmaf(ww, h.z, acc.z);
            acc.w = fmaf(ww, h.w, acc.w);
        }
    }
    #pragma unroll
    for (int m = 32; m; m >>= 1) {
        laWa += __shfl_xor(laWa, m);
        laWs += __shfl_xor(laWs, m);
        laSa += __shfl_xor(laSa, m);
        laSs += __shfl_xor(laSs, m);
    }
    acc.x += __shfl_xor(acc.x, 32);
    acc.y += __shfl_xor(acc.y, 32);
    acc.z += __shfl_xor(acc.z, 32);
    acc.w += __shfl_xor(acc.w, 32);
    const float denom = fmaxf(laWa - laSa, 1e-12f);
    const float4 hv = ((const float4*)(H + (size_t)anchor * 128))[qlane];
    float4 v;
    v.x = (acc.x - laSa * hv.x) / denom;
    v.y = (acc.y - laSa * hv.y) / denom;
    v.z = (acc.z - laSa * hv.z) / denom;
    v.w = (acc.w - laSa * hv.w) / denom;
    const float scale = (laWs - laSs) / denom;
    float n2 = v.x * v.x + v.y * v.y + v.z * v.z + v.w * v.w;
    #pragma unroll
    for (int m = 32; m; m >>= 1) n2 += __shfl_xor(n2, m);
    n2 *= 0.5f;
    const float na = sqrtf(n2);
    const float invA = 1.0f / fmaxf(na, 1e-6f);
    const float ns = fabsf(scale) * na;
    const float sgnscale = (ns > 0.f) ? (scale / fmaxf(ns, 1e-6f)) : scale;
    const float sc = half ? sgnscale : invA;
    float4 res = make_float4(v.x * sc, v.y * sc, v.z * sc, v.w * sc);
    float4* dst = half ? outS : outA;
    dst[qlane] = res;
}

extern "C" void kernel_launch(void* const* d_in, const int* in_sizes, int n_in,
                              void* d_out, int out_size, void* d_ws, size_t ws_size,
                              hipStream_t stream) {
    const float* H      = (const float*)d_in[0];
    const float* pw     = (const float*)d_in[1];
    const int* anchor   = (const int*)d_in[2];
    const int* gid      = (const int*)d_in[3];
    const int* pn       = (const int*)d_in[4];
    const int* plen     = (const int*)d_in[5];
    float* out          = (float*)d_out;

    const int B = in_sizes[2];
    const int G = in_sizes[5];
    const int ND = in_sizes[0];           // N*128 floats
    const size_t hb_bytes = (size_t)ND * 2;

    const int wavesPerBlock = 4;
    const int blocks = (B + wavesPerBlock - 1) / wavesPerBlock;

    if (ws_size >= hb_bytes + (size_t)G * 4) {
        unsigned short* Hb = (unsigned short*)d_ws;
        int* offsp = (int*)((char*)d_ws + hb_bytes);
        const int n4 = ND / 4;
        convert_h_kernel<<<(n4 + 255) / 256, 256, 0, stream>>>(
            (const float4*)H, (uint2*)Hb, n4);
        scan_offsets_kernel<<<1, 1024, 0, stream>>>(plen, offsp, G);
        pf_loo_bf16<<<blocks, 256, 0, stream>>>(Hb, pw, anchor, gid, pn, plen,
                                                offsp, out, B, G);
    } else {
        int* offsp = (int*)d_ws;
        scan_offsets_kernel<<<1, 1024, 0, stream>>>(plen, offsp, G);
        pf_loo_f32<<<blocks, 256, 0, stream>>>(H, pw, anchor, gid, pn, plen,
                                               offsp, out, B, G);
    }
}

// Round 4
// 142.612 us; speedup vs baseline: 1.2600x; 1.0327x over previous
//
#include <hip/hip_runtime.h>
#include <hip/hip_bf16.h>

// Problem: MultiViewDGT_51745765982512
//   d_in[0] H [N,128] f32, d_in[1] port_w [L] f32, d_in[2] anchor [B] i32,
//   d_in[3] pf_gid [B] i32, d_in[4] port_nodes [L] i32, d_in[5] port_len [G] i32
//   out = concat(V_abs [B,128], V_sgn [B,128]) f32
//
// R4: group-dedup two-phase. B==G with uniform pf_gid => only ~63% of groups
// are referenced; R3 gathered per-sample (duplicated groups gathered twice).
// Phase 1 (group_sums): one wave per USED group -> S_abs[g][128] f32 + W_abs,
// W_sgn into ws (0.63x the bf16 row-gathers, which are the L2-miss-path
// bound at ~410 GB/s/XCD). Phase 2 (per_sample): read S_abs[gid] + LOO line
// scan + epilogue. Init kernel fuses convert/flags/scan as independent block
// roles (no cross-block ordering needed).

#define DDIM 128

__device__ inline unsigned bf_rne(float x) {
    unsigned u = __float_as_uint(x);
    return (u + 0x7FFFu + ((u >> 16) & 1u)) >> 16;
}

__device__ inline void unpack2(unsigned d, float& lo, float& hi) {
    lo = __uint_as_float(d << 16);
    hi = __uint_as_float(d & 0xFFFF0000u);
}

// Block roles: [0, nconv) convert H->bf16; nconv: used-flags; nconv+1: scan.
__global__ __launch_bounds__(1024) void init_kernel(
    const float4* __restrict__ H4, uint2* __restrict__ Hb, int n4,
    const int* __restrict__ plen, int* __restrict__ offs, int G,
    const int* __restrict__ pf_gid, int* __restrict__ used, int B, int nconv) {
    const int t = threadIdx.x;
    const int bb = blockIdx.x;
    if (bb < nconv) {
        const int i = bb * 1024 + t;
        if (i < n4) {
            const float4 v = H4[i];
            uint2 o;
            o.x = bf_rne(v.x) | (bf_rne(v.y) << 16);
            o.y = bf_rne(v.z) | (bf_rne(v.w) << 16);
            Hb[i] = o;
        }
        return;
    }
    if (bb == nconv) {
        for (int i = t; i < G; i += 1024) used[i] = 0;
        __syncthreads();
        for (int i = t; i < B; i += 1024) {
            const int g = pf_gid[i];
            if (g >= 0 && g < G) used[g] = 1;
        }
        return;
    }
    // scan role: exclusive prefix sum of plen -> offs
    __shared__ int part[1024];
    const int chunk = (G + 1023) >> 10;
    const int lo = min(t * chunk, G);
    const int hi = min(lo + chunk, G);
    int s = 0;
    for (int i = lo; i < hi; ++i) s += plen[i];
    part[t] = s;
    __syncthreads();
    #pragma unroll
    for (int ofs = 1; ofs < 1024; ofs <<= 1) {
        int v = (t >= ofs) ? part[t - ofs] : 0;
        __syncthreads();
        part[t] += v;
        __syncthreads();
    }
    int run = part[t] - s;
    for (int i = lo; i < hi; ++i) { offs[i] = run; run += plen[i]; }
}

// One wave per used group: S_abs[g][128] (f32), W_abs[g], W_sgn[g].
// Gather: 4 rows per dwordx4 (quarter q = lane>>4 handles row jj+q,
// s = lane&15 owns dims [8s, 8s+8)).
__global__ __launch_bounds__(256) void group_sums(
    const unsigned short* __restrict__ Hb,
    const float* __restrict__ pw, const int* __restrict__ pn,
    const int* __restrict__ plen, const int* __restrict__ offs,
    const int* __restrict__ used,
    float* __restrict__ Sabs, float* __restrict__ Wag,
    float* __restrict__ Wsg, int G) {
    const int g = blockIdx.x * (blockDim.x >> 6) + (threadIdx.x >> 6);
    const int lane = threadIdx.x & 63;
    const int q = lane >> 4;
    const int s = lane & 15;
    if (g >= G || !used[g]) return;

    const int off = offs[g];
    const int len = plen[g];

    float acc[8] = {0.f, 0.f, 0.f, 0.f, 0.f, 0.f, 0.f, 0.f};
    float laWa = 0.f, laWs = 0.f;

    for (int base = 0; base < len; base += 64) {
        const int jmax = min(64, len - base);
        float wl = 0.f;
        int nl = 0;  // padding: w=0 contributes nothing
        if (lane < jmax) {
            wl = pw[off + base + lane];
            nl = pn[off + base + lane];
        }
        laWa += fabsf(wl);
        laWs += wl;

        #pragma unroll 8
        for (int jj = 0; jj < 64; jj += 4) {
            const float ww = fabsf(__shfl(wl, jj + q));
            const int row = __shfl(nl, jj + q);
            const uint4 h = *((const uint4*)(Hb + (size_t)row * DDIM) + s);
            float f0, f1, f2, f3, f4, f5, f6, f7;
            unpack2(h.x, f0, f1);
            unpack2(h.y, f2, f3);
            unpack2(h.z, f4, f5);
            unpack2(h.w, f6, f7);
            acc[0] = fmaf(ww, f0, acc[0]);
            acc[1] = fmaf(ww, f1, acc[1]);
            acc[2] = fmaf(ww, f2, acc[2]);
            acc[3] = fmaf(ww, f3, acc[3]);
            acc[4] = fmaf(ww, f4, acc[4]);
            acc[5] = fmaf(ww, f5, acc[5]);
            acc[6] = fmaf(ww, f6, acc[6]);
            acc[7] = fmaf(ww, f7, acc[7]);
        }
    }

    #pragma unroll
    for (int m = 32; m; m >>= 1) {
        laWa += __shfl_xor(laWa, m);
        laWs += __shfl_xor(laWs, m);
    }
    #pragma unroll
    for (int k = 0; k < 8; ++k) {
        acc[k] += __shfl_xor(acc[k], 16);
        acc[k] += __shfl_xor(acc[k], 32);
    }

    if (q == 0) {
        float4* dst = (float4*)(Sabs + (size_t)g * DDIM);
        dst[2 * s] = make_float4(acc[0], acc[1], acc[2], acc[3]);
        dst[2 * s + 1] = make_float4(acc[4], acc[5], acc[6], acc[7]);
    }
    if (lane == 0) { Wag[g] = laWa; Wsg[g] = laWs; }
}

// One wave per sample: LOO + epilogue. Lane owns dims [2l, 2l+1].
__global__ __launch_bounds__(256) void per_sample(
    const unsigned short* __restrict__ Hb,
    const float* __restrict__ pw, const int* __restrict__ pn,
    const int* __restrict__ plen, const int* __restrict__ offs,
    const float* __restrict__ Sabs, const float* __restrict__ Wag,
    const float* __restrict__ Wsg,
    const int* __restrict__ anchor_idx, const int* __restrict__ pf_gid,
    float* __restrict__ out, int B, int G) {
    const int b = blockIdx.x * (blockDim.x >> 6) + (threadIdx.x >> 6);
    const int lane = threadIdx.x & 63;
    if (b >= B) return;

    float2* outA = (float2*)(out + (size_t)b * DDIM);
    float2* outS = (float2*)(out + ((size_t)B + b) * DDIM);

    const int g = pf_gid[b];
    if (!(g >= 0 && g < G)) {
        const float2 z = make_float2(0.f, 0.f);
        outA[lane] = z;
        outS[lane] = z;
        return;
    }

    const int anchor = anchor_idx[b];
    const int off = offs[g];
    const int len = plen[g];

    float selfa = 0.f, selfs = 0.f;
    for (int base = 0; base < len; base += 64) {
        const int jmax = min(64, len - base);
        if (lane < jmax) {
            const float w = pw[off + base + lane];
            const int n = pn[off + base + lane];
            if (n == anchor) { selfa += fabsf(w); selfs += w; }
        }
    }
    #pragma unroll
    for (int m = 32; m; m >>= 1) {
        selfa += __shfl_xor(selfa, m);
        selfs += __shfl_xor(selfs, m);
    }

    const float Wa = Wag[g];
    const float Wsn = Wsg[g];
    const float2 S = ((const float2*)(Sabs + (size_t)g * DDIM))[lane];
    const unsigned hb = *((const unsigned*)(Hb + (size_t)anchor * DDIM) + lane);
    float h0, h1;
    unpack2(hb, h0, h1);

    const float denom = fmaxf(Wa - selfa, 1e-12f);
    float2 v;
    v.x = (S.x - selfa * h0) / denom;
    v.y = (S.y - selfa * h1) / denom;
    const float scale = (Wsn - selfs) / denom;

    float n2 = v.x * v.x + v.y * v.y;
    #pragma unroll
    for (int m = 32; m; m >>= 1) n2 += __shfl_xor(n2, m);
    const float na = sqrtf(n2);

    const float invA = 1.0f / fmaxf(na, 1e-6f);
    const float ns = fabsf(scale) * na;
    const float sgnscale = (ns > 0.f) ? (scale / fmaxf(ns, 1e-6f)) : scale;

    outA[lane] = make_float2(v.x * invA, v.y * invA);
    outS[lane] = make_float2(v.x * sgnscale, v.y * sgnscale);
}

// fp32 single-kernel fallback if ws too small (kept from R2, correctness net)
__global__ __launch_bounds__(1024) void scan_only(
    const int* __restrict__ len, int* __restrict__ offs, int G) {
    __shared__ int part[1024];
    const int t = threadIdx.x;
    const int chunk = (G + 1023) >> 10;
    const int lo = min(t * chunk, G);
    const int hi = min(lo + chunk, G);
    int s = 0;
    for (int i = lo; i < hi; ++i) s += len[i];
    part[t] = s;
    __syncthreads();
    #pragma unroll
    for (int ofs = 1; ofs < 1024; ofs <<= 1) {
        int v = (t >= ofs) ? part[t - ofs] : 0;
        __syncthreads();
        part[t] += v;
        __syncthreads();
    }
    int run = part[t] - s;
    for (int i = lo; i < hi; ++i) { offs[i] = run; run += len[i]; }
}

__global__ __launch_bounds__(256) void pf_loo_f32(
    const float* __restrict__ H, const float* __restrict__ pw,
    const int* __restrict__ anchor_idx, const int* __restrict__ pf_gid,
    const int* __restrict__ pn, const int* __restrict__ plen,
    const int* __restrict__ offs, float* __restrict__ out, int B, int G) {
    const int b = blockIdx.x * (blockDim.x >> 6) + (threadIdx.x >> 6);
    const int lane = threadIdx.x & 63;
    const int half = lane >> 5;
    const int qlane = lane & 31;
    if (b >= B) return;
    float4* outA = (float4*)(out + (size_t)b * DDIM);
    float4* outS = (float4*)(out + ((size_t)B + b) * DDIM);
    const int gid = pf_gid[b];
    if (!(gid >= 0 && gid < G)) {
        float4 z = make_float4(0.f, 0.f, 0.f, 0.f);
        if (half == 0) { outA[qlane] = z; outS[qlane] = z; }
        return;
    }
    const int anchor = anchor_idx[b];
    const int off = offs[gid];
    const int len = plen[gid];
    float4 acc = make_float4(0.f, 0.f, 0.f, 0.f);
    float laWa = 0.f, laWs = 0.f, laSa = 0.f, laSs = 0.f;
    for (int base = 0; base < len; base += 64) {
        const int jmax = min(64, len - base);
        float wl = 0.f;
        int nl = 0;
        if (lane < jmax) { wl = pw[off + base + lane]; nl = pn[off + base + lane]; }
        const float wla = fabsf(wl);
        laWa += wla; laWs += wl;
        if (nl == anchor) { laSa += wla; laSs += wl; }
        #pragma unroll 8
        for (int jj = 0; jj < 64; jj += 2) {
            const float ww = fabsf(__shfl(wl, jj + half));
            const int row = __shfl(nl, jj + half);
            const float4 h = ((const float4*)(H + (size_t)row * DDIM))[qlane];
            acc.x = fmaf(ww, h.x, acc.x);
            acc.y = fmaf(ww, h.y, acc.y);
            acc.z = fmaf(ww, h.z, acc.z);
            acc.w = fmaf(ww, h.w, acc.w);
        }
    }
    #pragma unroll
    for (int m = 32; m; m >>= 1) {
        laWa += __shfl_xor(laWa, m);
        laWs += __shfl_xor(laWs, m);
        laSa += __shfl_xor(laSa, m);
        laSs += __shfl_xor(laSs, m);
    }
    acc.x += __shfl_xor(acc.x, 32);
    acc.y += __shfl_xor(acc.y, 32);
    acc.z += __shfl_xor(acc.z, 32);
    acc.w += __shfl_xor(acc.w, 32);
    const float denom = fmaxf(laWa - laSa, 1e-12f);
    const float4 hv = ((const float4*)(H + (size_t)anchor * DDIM))[qlane];
    float4 v;
    v.x = (acc.x - laSa * hv.x) / denom;
    v.y = (acc.y - laSa * hv.y) / denom;
    v.z = (acc.z - laSa * hv.z) / denom;
    v.w = (acc.w - laSa * hv.w) / denom;
    const float scale = (laWs - laSs) / denom;
    float n2 = v.x * v.x + v.y * v.y + v.z * v.z + v.w * v.w;
    #pragma unroll
    for (int m = 32; m; m >>= 1) n2 += __shfl_xor(n2, m);
    n2 *= 0.5f;
    const float na = sqrtf(n2);
    const float invA = 1.0f / fmaxf(na, 1e-6f);
    const float ns = fabsf(scale) * na;
    const float sgnscale = (ns > 0.f) ? (scale / fmaxf(ns, 1e-6f)) : scale;
    const float sc = half ? sgnscale : invA;
    float4 res = make_float4(v.x * sc, v.y * sc, v.z * sc, v.w * sc);
    float4* dst = half ? outS : outA;
    dst[qlane] = res;
}

extern "C" void kernel_launch(void* const* d_in, const int* in_sizes, int n_in,
                              void* d_out, int out_size, void* d_ws, size_t ws_size,
                              hipStream_t stream) {
    const float* H      = (const float*)d_in[0];
    const float* pw     = (const float*)d_in[1];
    const int* anchor   = (const int*)d_in[2];
    const int* gid      = (const int*)d_in[3];
    const int* pn       = (const int*)d_in[4];
    const int* plen     = (const int*)d_in[5];
    float* out          = (float*)d_out;

    const int B = in_sizes[2];
    const int G = in_sizes[5];
    const int ND = in_sizes[0];                 // N*128 floats
    const size_t hb_bytes = (size_t)ND * 2;     // bf16 H
    const size_t sabs_bytes = (size_t)G * DDIM * 4;
    const size_t need = hb_bytes + sabs_bytes + (size_t)G * 4 * 4;

    if (ws_size >= need) {
        char* p = (char*)d_ws;
        unsigned short* Hb = (unsigned short*)p;        p += hb_bytes;
        float* Sabs        = (float*)p;                 p += sabs_bytes;
        int* offsp         = (int*)p;                   p += (size_t)G * 4;
        int* usedp         = (int*)p;                   p += (size_t)G * 4;
        float* Wag         = (float*)p;                 p += (size_t)G * 4;
        float* Wsg         = (float*)p;

        const int n4 = ND / 4;
        const int nconv = (n4 + 1023) / 1024;
        init_kernel<<<nconv + 2, 1024, 0, stream>>>(
            (const float4*)H, (uint2*)Hb, n4, plen, offsp, G, gid, usedp, B, nconv);

        const int gblocks = (G + 3) / 4;
        group_sums<<<gblocks, 256, 0, stream>>>(Hb, pw, pn, plen, offsp, usedp,
                                                Sabs, Wag, Wsg, G);

        const int sblocks = (B + 3) / 4;
        per_sample<<<sblocks, 256, 0, stream>>>(Hb, pw, pn, plen, offsp, Sabs,
                                                Wag, Wsg, anchor, gid, out, B, G);
    } else {
        int* offsp = (int*)d_ws;
        scan_only<<<1, 1024, 0, stream>>>(plen, offsp, G);
        const int blocks = (B + 3) / 4;
        pf_loo_f32<<<blocks, 256, 0, stream>>>(H, pw, anchor, gid, pn, plen,
                                               offsp, out, B, G);
    }
}